// Round 6
// baseline (1323.518 us; speedup 1.0000x reference)
//
#include <hip/hip_runtime.h>
#include <cstdint>

#define NB 32
#define IC 2048
#define IK 16
#define OC 64
#define OD 32
#define CELLS (NB*OC*OD)   // 65536

typedef __fp16 h2 __attribute__((ext_vector_type(2)));

__device__ __forceinline__ h2 pk2(float a, float b) {
#if __has_builtin(__builtin_amdgcn_cvt_pkrtz)
  return __builtin_amdgcn_cvt_pkrtz(a, b);
#else
  h2 r; r.x = (__fp16)a; r.y = (__fp16)b; return r;
#endif
}

__device__ __forceinline__ float fdot2a(h2 a, h2 b, float c) {
#if __has_builtin(__builtin_amdgcn_fdot2)
  return __builtin_amdgcn_fdot2(a, b, c, false);
#else
  return c + (float)a.x*(float)b.x + (float)a.y*(float)b.y;
#endif
}

__device__ __forceinline__ h2 bch2(unsigned int u) { return __builtin_bit_cast(h2, u); }

// One routing pass. ITER: 0 = first iteration (c == 1/64, just sum u_hat),
// 1 = second (b_prev = 0, writes b_out = A1), 2 = third (reads b_in = A1).
//
// R3-R5 lesson: the allocator pins VGPR=128 (4 waves/EU target) regardless of
// __launch_bounds__ 2nd arg or amdgpu_waves_per_eu, and the old 512-thread
// layout (s_acc[32][4] = 128 regs alone) spilled ~800 MB/dispatch to scratch.
// So: 1024 threads/wg, each thread owns (o, d-PAIR) -> s_acc[32][2] = 64 regs,
// wh[2][8] = 16, usav[8][2] = 16; working set ~115 regs fits the 128 cap.
// 16 waves/wg = 4 waves/SIMD at 1 wg/CU = the allocator's own occupancy target.
//
// Thread map: o = t>>4 (64 o), dh = t&15 (16 d-pairs), d = dh*2 + j (j=0..1).
// W[i] rows held in registers as packed f16; u_hat via v_dot2_f32_f16.
// Per-wg partial s flushed non-atomically to part[wg]; reduce kernel sums.
template<int ITER>
__global__ __launch_bounds__(1024)
void caps_pass(const float* __restrict__ xg, const float* __restrict__ Wg,
               const float* __restrict__ vin, const float* __restrict__ bin,
               float* __restrict__ bout, float* __restrict__ part, int chunk)
{
  __shared__ __align__(16) unsigned int x_h[8][NB][8];  // f16x2-packed x, 8 KB
  __shared__ float agr_s[NB][OC];                       // 8 KB

  const int t    = threadIdx.x;      // 0..1023
  const int o    = t >> 4;           // 0..63
  const int dh   = t & 15;           // 0..15
  const int d0   = dh * 2;
  const int lane = t & 63;
  const int i0   = blockIdx.x * chunk;

  float s_acc[NB][2];
#pragma unroll
  for (int b = 0; b < NB; ++b) { s_acc[b][0] = 0.f; s_acc[b][1] = 0.f; }

  for (int g = 0; g < chunk; g += 8) {
    const int ibase = i0 + g;
    // stage x[all b, ibase..ibase+8, :] as packed f16 (exactly 1 float4/thread)
    {
      const int f = t;                     // f = b*32 + ii*4 + k4
      const int b = f >> 5, rem = f & 31, ii = rem >> 2, k4 = rem & 3;
      const float4 xv = *(const float4*)&xg[((size_t)b*IC + ibase + ii)*IK + k4*4];
      x_h[ii][b][k4*2]   = __builtin_bit_cast(unsigned int, pk2(xv.x, xv.y));
      x_h[ii][b][k4*2+1] = __builtin_bit_cast(unsigned int, pk2(xv.z, xv.w));
    }
    __syncthreads();

#pragma unroll 1
    for (int ii = 0; ii < 8; ++ii) {
      const int i = ibase + ii;
      // load W[i, o, d0..d0+1, :] (128 B contiguous per thread) -> packed f16
      const float4* Wp = (const float4*)(Wg + (((size_t)i*OC + o)*OD + d0)*IK);
      h2 wh[2][8];
#pragma unroll
      for (int j = 0; j < 2; ++j)
#pragma unroll
        for (int q = 0; q < 4; ++q) {
          const float4 w4 = Wp[j*4 + q];
          wh[j][q*2]   = pk2(w4.x, w4.y);
          wh[j][q*2+1] = pk2(w4.z, w4.w);
        }

      if (ITER == 0) {
#pragma unroll
        for (int b = 0; b < NB; ++b) {
          const uint4* xp = (const uint4*)&x_h[ii][b][0];
          const uint4 xa = xp[0], xb4 = xp[1];
          const h2 xh[8] = {bch2(xa.x),bch2(xa.y),bch2(xa.z),bch2(xa.w),
                            bch2(xb4.x),bch2(xb4.y),bch2(xb4.z),bch2(xb4.w)};
          float a0 = 0.f, a1 = 0.f;
#pragma unroll
          for (int q = 0; q < 8; ++q) {
            a0 = fdot2a(wh[0][q], xh[q], a0);
            a1 = fdot2a(wh[1][q], xh[q], a1);
          }
          s_acc[b][0] += a0; s_acc[b][1] += a1;
        }
      } else {
#pragma unroll
        for (int bbase = 0; bbase < NB; bbase += 8) {
          float usav[8][2];
#pragma unroll
          for (int bb = 0; bb < 8; ++bb) {
            const int b = bbase + bb;
            const uint4* xp = (const uint4*)&x_h[ii][b][0];
            const uint4 xa = xp[0], xb4 = xp[1];
            const h2 xh[8] = {bch2(xa.x),bch2(xa.y),bch2(xa.z),bch2(xa.w),
                              bch2(xb4.x),bch2(xb4.y),bch2(xb4.z),bch2(xb4.w)};
            float u0 = 0.f, u1 = 0.f;
#pragma unroll
            for (int q = 0; q < 8; ++q) {
              u0 = fdot2a(wh[0][q], xh[q], u0);
              u1 = fdot2a(wh[1][q], xh[q], u1);
            }
            usav[bb][0] = u0; usav[bb][1] = u1;
            // agreement = sum_d u_hat*v ; reduce over the 16 dh lanes (same o)
            const float2 vv = *(const float2*)&vin[((size_t)b*OC + o)*OD + d0];
            float ap = u0*vv.x + u1*vv.y;
            ap += __shfl_xor(ap, 1);
            ap += __shfl_xor(ap, 2);
            ap += __shfl_xor(ap, 4);
            ap += __shfl_xor(ap, 8);
            if (dh == 0) {
              float bn = ap;
              if (ITER == 2) bn += bin[((size_t)b*IC + i)*OC + o];
              if (ITER == 1) bout[((size_t)b*IC + i)*OC + o] = bn;
              agr_s[b][o] = bn;
            }
          }
          __syncthreads();
          // wave-redundant softmax over the 64 o's (row fits one wave)
#pragma unroll
          for (int bb = 0; bb < 8; ++bb) {
            const int b = bbase + bb;
            const float a = agr_s[b][lane];
            float m = a;
#pragma unroll
            for (int off = 1; off < 64; off <<= 1) m = fmaxf(m, __shfl_xor(m, off));
            const float e = __expf(a - m);
            float se = e;
#pragma unroll
            for (int off = 1; off < 64; off <<= 1) se += __shfl_xor(se, off);
            const float cl = e / se;          // c for o = lane
            const float cm = __shfl(cl, o);   // c for my o
            s_acc[b][0] += cm * usav[bb][0];
            s_acc[b][1] += cm * usav[bb][1];
          }
        }
      }
    }
    __syncthreads();
  }

  // flush per-wg partial s (coalesced float2 stores)
  const float scale = (ITER == 0) ? (1.0f/64.0f) : 1.0f;
  float* pp = part + (size_t)blockIdx.x * CELLS;
#pragma unroll
  for (int b = 0; b < NB; ++b) {
    float2 st;
    st.x = s_acc[b][0]*scale; st.y = s_acc[b][1]*scale;
    *(float2*)&pp[((size_t)b*OC + o)*OD + d0] = st;
  }
}

// Sum nwg partial buffers and apply squash. One wave per (b,o) row:
// lanes 0..31 = d, two half-lane groups split the wg dimension.
__global__ __launch_bounds__(64)
void caps_reduce(const float* __restrict__ part, int nwg, float* __restrict__ vout)
{
  const int r = blockIdx.x;            // row = b*OC + o, 0..2047
  const int d = threadIdx.x & 31;
  const int h = threadIdx.x >> 5;
  const size_t cell = (size_t)r*OD + d;
  const int wh = nwg >> 1;
  const float* p = part + cell + (size_t)h*wh*CELLS;
  float s = 0.f;
#pragma unroll 4
  for (int w = 0; w < wh; ++w) s += p[(size_t)w*CELLS];
  s += __shfl_xor(s, 32);              // combine the two halves
  float n2 = s*s;
#pragma unroll
  for (int off = 1; off < 32; off <<= 1) n2 += __shfl_xor(n2, off);
  const float n = sqrtf(n2);
  const float f = n2 / ((1.f + n2)*(n + 1e-8f));   // squash factor, matches ref
  if (h == 0) vout[cell] = s*f;
}

extern "C" void kernel_launch(void* const* d_in, const int* in_sizes, int n_in,
                              void* d_out, int out_size, void* d_ws, size_t ws_size,
                              hipStream_t stream)
{
  const float* xg = (const float*)d_in[0];
  const float* Wg = (const float*)d_in[1];
  float* out = (float*)d_out;

  const size_t bbuf_bytes = (size_t)NB*IC*OC*sizeof(float);   // 16 MB (A1 logits)
  const size_t v_bytes    = (size_t)CELLS*sizeof(float);      // 256 KB
  int nwg = 256;
  while (nwg > 32 &&
         ((size_t)nwg*CELLS*sizeof(float) + bbuf_bytes + v_bytes) > ws_size)
    nwg >>= 1;
  const int chunk = IC / nwg;

  float* part = (float*)d_ws;
  float* bbuf = (float*)((char*)d_ws + (size_t)nwg*CELLS*sizeof(float));
  float* vbuf = (float*)((char*)bbuf + bbuf_bytes);

  // iter 1: c = 1/64 exactly -> plain sum of u_hat
  caps_pass<0><<<nwg, 1024, 0, stream>>>(xg, Wg, nullptr, nullptr, nullptr, part, chunk);
  caps_reduce<<<NB*OC, 64, 0, stream>>>(part, nwg, vbuf);
  // iter 2: A1 = u.v1, c = softmax(A1); store A1
  caps_pass<1><<<nwg, 1024, 0, stream>>>(xg, Wg, vbuf, nullptr, bbuf, part, chunk);
  caps_reduce<<<NB*OC, 64, 0, stream>>>(part, nwg, vbuf);
  // iter 3: c = softmax(A1 + u.v2)
  caps_pass<2><<<nwg, 1024, 0, stream>>>(xg, Wg, vbuf, bbuf, nullptr, part, chunk);
  caps_reduce<<<NB*OC, 64, 0, stream>>>(part, nwg, out);
}

// Round 7
// 664.926 us; speedup vs baseline: 1.9905x; 1.9905x over previous
//
#include <hip/hip_runtime.h>
#include <cstdint>

#define NB 32
#define NBW 16                     // batch elements per workgroup (b-split)
#define IC 2048
#define IK 16
#define OC 64
#define OD 32
#define PARTBLK (NBW*OC*OD)        // 32768 floats per wg partial
#define NCHUNK 128                 // i-chunks; grid = 2*NCHUNK (b-half fastest)

typedef __fp16 h2 __attribute__((ext_vector_type(2)));

__device__ __forceinline__ h2 pk2(float a, float b) {
#if __has_builtin(__builtin_amdgcn_cvt_pkrtz)
  return __builtin_amdgcn_cvt_pkrtz(a, b);
#else
  h2 r; r.x = (__fp16)a; r.y = (__fp16)b; return r;
#endif
}

__device__ __forceinline__ float fdot2a(h2 a, h2 b, float c) {
#if __has_builtin(__builtin_amdgcn_fdot2)
  return __builtin_amdgcn_fdot2(a, b, c, false);
#else
  return c + (float)a.x*(float)b.x + (float)a.y*(float)b.y;
#endif
}

__device__ __forceinline__ h2 bch2(unsigned int u) { return __builtin_bit_cast(h2, u); }

// Routing pass, s-tile in LDS (R3-R6 lesson: allocator budgets 65536
// lane-regs/wg -> register-resident s[32][64][32] can never fit; spills).
// wg = (i-chunk ci, b-half bh): handles b in [bh*16, bh*16+16), all o,d,
// i in [ci*chunk, +chunk). Twin wgs (same ci) adjacent in blockIdx so the
// second W stream hits L3. 512 threads: o = t>>3, dq = t&7 (d-quad).
// s_lds[16][64][32] f32 = 128 KB, XOR quad-swizzle (T2/G4) kills the
// 128B-row-stride bank conflicts. Per-thread regs ~110 < 128 cap.
template<int ITER>
__global__ __launch_bounds__(512)
void caps_pass(const float* __restrict__ xg, const float* __restrict__ Wg,
               const float* __restrict__ vin, const float* __restrict__ bin,
               float* __restrict__ bout, float* __restrict__ part, int chunk)
{
  __shared__ float s_lds[NBW*OC*OD];                    // 128 KB
  __shared__ __align__(16) unsigned int x_h[8][NBW][8]; // 4 KB (f16x2 x)
  __shared__ float agr_s[NBW][OC];                      // 4 KB

  const int t    = threadIdx.x;
  const int o    = t >> 3;          // 0..63
  const int dq   = t & 7;           // logical d-quad, d = dq*4+j
  const int d0   = dq * 4;
  const int lane = t & 63;
  const int ci   = blockIdx.x >> 1;
  const int bh   = blockIdx.x & 1;
  const int i0   = ci * chunk;
  const int bg0  = bh * NBW;
  // swizzled LDS quad for this thread's (o,dq) cells
  const int qp   = dq ^ (o & 7);
  // per-(b) base: s_lds[(b*OC+o)*OD + qp*4]
  const int sbase = o * OD + qp * 4;

  for (int idx = t; idx < NBW*OC*OD; idx += 512) s_lds[idx] = 0.f;
  // staging barrier below also orders zero-init vs first s update

  for (int g = 0; g < chunk; g += 8) {
    const int ibase = i0 + g;
    // stage x[bg0..+16, ibase..+8, :] as packed f16 — exactly 1 float4/thread
    {
      const int b = t >> 5, rem = t & 31, ii = rem >> 2, k4 = rem & 3;
      const float4 xv = *(const float4*)&xg[((size_t)(bg0 + b)*IC + ibase + ii)*IK + k4*4];
      x_h[ii][b][k4*2]   = __builtin_bit_cast(unsigned int, pk2(xv.x, xv.y));
      x_h[ii][b][k4*2+1] = __builtin_bit_cast(unsigned int, pk2(xv.z, xv.w));
    }
    __syncthreads();

#pragma unroll 1
    for (int ii = 0; ii < 8; ++ii) {
      const int i = ibase + ii;
      // W[i, o, d0..d0+3, :] = 256 B contiguous per thread -> packed f16
      const float4* Wp = (const float4*)(Wg + (((size_t)i*OC + o)*OD + d0)*IK);
      h2 wh[4][8];
#pragma unroll
      for (int j = 0; j < 4; ++j)
#pragma unroll
        for (int q = 0; q < 4; ++q) {
          const float4 w4 = Wp[j*4 + q];
          wh[j][q*2]   = pk2(w4.x, w4.y);
          wh[j][q*2+1] = pk2(w4.z, w4.w);
        }

      if (ITER == 0) {
#pragma unroll
        for (int b = 0; b < NBW; ++b) {
          const uint4* xp = (const uint4*)&x_h[ii][b][0];
          const uint4 xa = xp[0], xb4 = xp[1];
          const h2 xh[8] = {bch2(xa.x),bch2(xa.y),bch2(xa.z),bch2(xa.w),
                            bch2(xb4.x),bch2(xb4.y),bch2(xb4.z),bch2(xb4.w)};
          float a0=0.f, a1=0.f, a2=0.f, a3=0.f;
#pragma unroll
          for (int q = 0; q < 8; ++q) {
            a0 = fdot2a(wh[0][q], xh[q], a0);
            a1 = fdot2a(wh[1][q], xh[q], a1);
            a2 = fdot2a(wh[2][q], xh[q], a2);
            a3 = fdot2a(wh[3][q], xh[q], a3);
          }
          float4* sp = (float4*)&s_lds[b*(OC*OD) + sbase];
          float4 sv = *sp;
          sv.x += a0; sv.y += a1; sv.z += a2; sv.w += a3;
          *sp = sv;
        }
      } else {
#pragma unroll
        for (int bbase = 0; bbase < NBW; bbase += 8) {
          float usav[8][4];
#pragma unroll
          for (int bb = 0; bb < 8; ++bb) {
            const int b = bbase + bb;
            const uint4* xp = (const uint4*)&x_h[ii][b][0];
            const uint4 xa = xp[0], xb4 = xp[1];
            const h2 xh[8] = {bch2(xa.x),bch2(xa.y),bch2(xa.z),bch2(xa.w),
                              bch2(xb4.x),bch2(xb4.y),bch2(xb4.z),bch2(xb4.w)};
            float u0=0.f, u1=0.f, u2=0.f, u3=0.f;
#pragma unroll
            for (int q = 0; q < 8; ++q) {
              u0 = fdot2a(wh[0][q], xh[q], u0);
              u1 = fdot2a(wh[1][q], xh[q], u1);
              u2 = fdot2a(wh[2][q], xh[q], u2);
              u3 = fdot2a(wh[3][q], xh[q], u3);
            }
            usav[bb][0]=u0; usav[bb][1]=u1; usav[bb][2]=u2; usav[bb][3]=u3;
            // agreement = sum_d u*v, reduce over the 8 dq lanes (same o)
            const float4 vv = *(const float4*)&vin[((size_t)(bg0+b)*OC + o)*OD + d0];
            float ap = u0*vv.x + u1*vv.y + u2*vv.z + u3*vv.w;
            ap += __shfl_xor(ap, 1);
            ap += __shfl_xor(ap, 2);
            ap += __shfl_xor(ap, 4);
            if (dq == 0) {
              float bn = ap;
              if (ITER == 2) bn += bin[((size_t)(bg0+b)*IC + i)*OC + o];
              if (ITER == 1) bout[((size_t)(bg0+b)*IC + i)*OC + o] = bn;
              agr_s[b][o] = bn;
            }
          }
          __syncthreads();
          // wave-redundant softmax over the 64 o's + s accumulation in LDS
#pragma unroll
          for (int bb = 0; bb < 8; ++bb) {
            const int b = bbase + bb;
            const float a = agr_s[b][lane];
            float m = a;
#pragma unroll
            for (int off = 1; off < 64; off <<= 1) m = fmaxf(m, __shfl_xor(m, off));
            const float e = __expf(a - m);
            float se = e;
#pragma unroll
            for (int off = 1; off < 64; off <<= 1) se += __shfl_xor(se, off);
            const float cl = e / se;          // c for o = lane
            const float cm = __shfl(cl, o);   // c for my o
            float4* sp = (float4*)&s_lds[b*(OC*OD) + sbase];
            float4 sv = *sp;
            sv.x += cm*usav[bb][0]; sv.y += cm*usav[bb][1];
            sv.z += cm*usav[bb][2]; sv.w += cm*usav[bb][3];
            *sp = sv;
          }
          // next write to these agr_s rows happens only after the NEXT
          // barrier (wrap b+16 -> next ii's first batch), so reads are safe
        }
      }
    }
    __syncthreads();   // protect x_h restage (and s zero-init on g==0)
  }

  // flush per-wg partial s (coalesced float4, un-swizzled to logical d)
  const float scale = (ITER == 0) ? (1.0f/64.0f) : 1.0f;
  float* pp = part + (size_t)blockIdx.x * PARTBLK;
#pragma unroll
  for (int b = 0; b < NBW; ++b) {
    float4 sv = *(float4*)&s_lds[b*(OC*OD) + sbase];
    float4 st;
    st.x = sv.x*scale; st.y = sv.y*scale; st.z = sv.z*scale; st.w = sv.w*scale;
    *(float4*)&pp[((size_t)b*OC + o)*OD + d0] = st;
  }
}

// Sum partials over i-chunks and apply squash. One 64-thr block per (b,o):
// lanes 0..31 = d; the two 32-lane halves split the chunk range.
__global__ __launch_bounds__(64)
void caps_reduce(const float* __restrict__ part, int nchunk, float* __restrict__ vout)
{
  const int r  = blockIdx.x;           // b*OC + o, 0..2047
  const int b  = r >> 6, o = r & 63;
  const int bh = b >> 4, bl = b & 15;
  const int d  = threadIdx.x & 31;
  const int h  = threadIdx.x >> 5;
  const size_t cellp = ((size_t)(bl*OC + o))*OD + d;
  const int half = nchunk >> 1;
  const float* p = part + ((size_t)(h*half)*2 + bh)*PARTBLK + cellp;
  float s = 0.f;
#pragma unroll 4
  for (int w = 0; w < half; ++w) s += p[(size_t)w*2*PARTBLK];
  s += __shfl_xor(s, 32);              // combine the two halves
  float n2 = s*s;
#pragma unroll
  for (int off = 1; off < 32; off <<= 1) n2 += __shfl_xor(n2, off);
  const float n = sqrtf(n2);
  const float f = n2 / ((1.f + n2)*(n + 1e-8f));   // squash, matches ref
  if (h == 0) vout[(size_t)r*OD + d] = s*f;
}

extern "C" void kernel_launch(void* const* d_in, const int* in_sizes, int n_in,
                              void* d_out, int out_size, void* d_ws, size_t ws_size,
                              hipStream_t stream)
{
  const float* xg = (const float*)d_in[0];
  const float* Wg = (const float*)d_in[1];
  float* out = (float*)d_out;

  const size_t bbuf_bytes = (size_t)NB*IC*OC*sizeof(float);   // 16 MB logits
  const size_t v_bytes    = (size_t)NB*OC*OD*sizeof(float);   // 256 KB
  int nchunk = NCHUNK;                                        // part = 32 MB
  while (nchunk > 16 &&
         ((size_t)nchunk*2*PARTBLK*sizeof(float) + bbuf_bytes + v_bytes) > ws_size)
    nchunk >>= 1;
  const int chunk = IC / nchunk;
  const int nwg = nchunk * 2;

  float* part = (float*)d_ws;
  float* bbuf = (float*)((char*)d_ws + (size_t)nwg*PARTBLK*sizeof(float));
  float* vbuf = (float*)((char*)bbuf + bbuf_bytes);

  // iter 1: c = 1/64 exactly -> plain sum of u_hat
  caps_pass<0><<<nwg, 512, 0, stream>>>(xg, Wg, nullptr, nullptr, nullptr, part, chunk);
  caps_reduce<<<NB*OC, 64, 0, stream>>>(part, nchunk, vbuf);
  // iter 2: A1 = u.v1, c = softmax(A1); store A1
  caps_pass<1><<<nwg, 512, 0, stream>>>(xg, Wg, vbuf, nullptr, bbuf, part, chunk);
  caps_reduce<<<NB*OC, 64, 0, stream>>>(part, nchunk, vbuf);
  // iter 3: c = softmax(A1 + u.v2)
  caps_pass<2><<<nwg, 512, 0, stream>>>(xg, Wg, vbuf, bbuf, nullptr, part, chunk);
  caps_reduce<<<NB*OC, 64, 0, stream>>>(part, nchunk, out);
}

// Round 8
// 658.432 us; speedup vs baseline: 2.0101x; 1.0099x over previous
//
#include <hip/hip_runtime.h>
#include <cstdint>

#define NB 32
#define NBW 8                      // batch elements per workgroup (b-quarter)
#define IC 2048
#define IK 16
#define OC 64
#define OD 32
#define PARTBLK (NBW*OC*OD)        // 16384 floats (64 KB) per wg partial
#define NCHUNK 128                 // i-chunks; grid = 4*NCHUNK

typedef __fp16 h2 __attribute__((ext_vector_type(2)));

__device__ __forceinline__ h2 pk2(float a, float b) {
#if __has_builtin(__builtin_amdgcn_cvt_pkrtz)
  return __builtin_amdgcn_cvt_pkrtz(a, b);
#else
  h2 r; r.x = (__fp16)a; r.y = (__fp16)b; return r;
#endif
}

__device__ __forceinline__ float fdot2a(h2 a, h2 b, float c) {
#if __has_builtin(__builtin_amdgcn_fdot2)
  return __builtin_amdgcn_fdot2(a, b, c, false);
#else
  return c + (float)a.x*(float)b.x + (float)a.y*(float)b.y;
#endif
}

__device__ __forceinline__ h2 bch2(unsigned int u) { return __builtin_bit_cast(h2, u); }

// Routing pass, s-tile in LDS. R7 lesson: NBW=16 (128 KB s) -> 1 wg/CU,
// 2 waves/SIMD, latency-bound at 12% HBM. NBW=8: s=64 KB, ~68 KB total LDS
// -> 2 wgs/CU, 4 waves/SIMD. Four twin wgs (b-quarters of one i-chunk) are
// placed on the SAME XCD via bid%8 swizzle so W re-reads hit that XCD's L2.
// 512 threads: o = t>>3, dq = t&7 (d-quad). XOR quad-swizzle on s_lds rows.
template<int ITER>
__global__ __launch_bounds__(512)
void caps_pass(const float* __restrict__ xg, const float* __restrict__ Wg,
               const float* __restrict__ vin, const float* __restrict__ bin,
               float* __restrict__ bout, float* __restrict__ part,
               int chunk, int nchunk)
{
  __shared__ float s_lds[NBW*OC*OD];                    // 64 KB
  __shared__ __align__(16) unsigned int x_h[8][NBW][8]; // 2 KB (f16x2 x)
  __shared__ float agr_s[NBW][OC];                      // 2 KB

  const int t    = threadIdx.x;
  const int o    = t >> 3;          // 0..63
  const int dq   = t & 7;           // d-quad, d = dq*4+j
  const int d0   = dq * 4;
  const int lane = t & 63;

  // decode (ci, bq) with XCD co-location: bid%8 = XCD (round-robin heuristic);
  // the 4 twins of one ci are consecutive slots on one XCD -> share its L2.
  const int bid = blockIdx.x;
  int ci, bq;
  if ((nchunk & 7) == 0) {
    const int xcd = bid & 7, slot = bid >> 3;
    ci = xcd * (nchunk >> 3) + (slot >> 2);
    bq = slot & 3;
  } else { ci = bid >> 2; bq = bid & 3; }
  const int i0  = ci * chunk;
  const int bg0 = bq * NBW;
  const int qp  = dq ^ (o & 7);     // swizzled quad (bank-conflict break)
  const int sbase = o * OD + qp * 4;

  for (int idx = t; idx < NBW*OC*OD; idx += 512) s_lds[idx] = 0.f;

  for (int g = 0; g < chunk; g += 8) {
    const int ibase = i0 + g;
    // stage x[bg0..+8, ibase..+8, :] packed f16 — 256 float4 over 512 thr
    if (t < 256) {
      const int b = t >> 5, rem = t & 31, ii = rem >> 2, k4 = rem & 3;
      const float4 xv = *(const float4*)&xg[((size_t)(bg0 + b)*IC + ibase + ii)*IK + k4*4];
      x_h[ii][b][k4*2]   = __builtin_bit_cast(unsigned int, pk2(xv.x, xv.y));
      x_h[ii][b][k4*2+1] = __builtin_bit_cast(unsigned int, pk2(xv.z, xv.w));
    }
    __syncthreads();

#pragma unroll 1
    for (int ii = 0; ii < 8; ++ii) {
      const int i = ibase + ii;
      // W[i, o, d0..d0+3, :] = 256 B contiguous per thread -> packed f16
      const float4* Wp = (const float4*)(Wg + (((size_t)i*OC + o)*OD + d0)*IK);
      h2 wh[4][8];
#pragma unroll
      for (int j = 0; j < 4; ++j)
#pragma unroll
        for (int q = 0; q < 4; ++q) {
          const float4 w4 = Wp[j*4 + q];
          wh[j][q*2]   = pk2(w4.x, w4.y);
          wh[j][q*2+1] = pk2(w4.z, w4.w);
        }

      if (ITER == 0) {
#pragma unroll
        for (int b = 0; b < NBW; ++b) {
          const uint4* xp = (const uint4*)&x_h[ii][b][0];
          const uint4 xa = xp[0], xb4 = xp[1];
          const h2 xh[8] = {bch2(xa.x),bch2(xa.y),bch2(xa.z),bch2(xa.w),
                            bch2(xb4.x),bch2(xb4.y),bch2(xb4.z),bch2(xb4.w)};
          float a0=0.f, a1=0.f, a2=0.f, a3=0.f;
#pragma unroll
          for (int q = 0; q < 8; ++q) {
            a0 = fdot2a(wh[0][q], xh[q], a0);
            a1 = fdot2a(wh[1][q], xh[q], a1);
            a2 = fdot2a(wh[2][q], xh[q], a2);
            a3 = fdot2a(wh[3][q], xh[q], a3);
          }
          float4* sp = (float4*)&s_lds[b*(OC*OD) + sbase];
          float4 sv = *sp;
          sv.x += a0; sv.y += a1; sv.z += a2; sv.w += a3;
          *sp = sv;
        }
      } else {
        float usav[NBW][4];
#pragma unroll
        for (int b = 0; b < NBW; ++b) {
          const uint4* xp = (const uint4*)&x_h[ii][b][0];
          const uint4 xa = xp[0], xb4 = xp[1];
          const h2 xh[8] = {bch2(xa.x),bch2(xa.y),bch2(xa.z),bch2(xa.w),
                            bch2(xb4.x),bch2(xb4.y),bch2(xb4.z),bch2(xb4.w)};
          float u0=0.f, u1=0.f, u2=0.f, u3=0.f;
#pragma unroll
          for (int q = 0; q < 8; ++q) {
            u0 = fdot2a(wh[0][q], xh[q], u0);
            u1 = fdot2a(wh[1][q], xh[q], u1);
            u2 = fdot2a(wh[2][q], xh[q], u2);
            u3 = fdot2a(wh[3][q], xh[q], u3);
          }
          usav[b][0]=u0; usav[b][1]=u1; usav[b][2]=u2; usav[b][3]=u3;
          // agreement = sum_d u*v, reduce over the 8 dq lanes (same o)
          const float4 vv = *(const float4*)&vin[((size_t)(bg0+b)*OC + o)*OD + d0];
          float ap = u0*vv.x + u1*vv.y + u2*vv.z + u3*vv.w;
          ap += __shfl_xor(ap, 1);
          ap += __shfl_xor(ap, 2);
          ap += __shfl_xor(ap, 4);
          if (dq == 0) {
            float bn = ap;
            if (ITER == 2) bn += bin[((size_t)(bg0+b)*IC + i)*OC + o];
            if (ITER == 1) bout[((size_t)(bg0+b)*IC + i)*OC + o] = bn;
            agr_s[b][o] = bn;
          }
        }
        __syncthreads();
        // wave-redundant softmax over the 64 o's + s accumulation in LDS
#pragma unroll
        for (int b = 0; b < NBW; ++b) {
          const float a = agr_s[b][lane];
          float m = a;
#pragma unroll
          for (int off = 1; off < 64; off <<= 1) m = fmaxf(m, __shfl_xor(m, off));
          const float e = __expf(a - m);
          float se = e;
#pragma unroll
          for (int off = 1; off < 64; off <<= 1) se += __shfl_xor(se, off);
          const float cl = e / se;          // c for o = lane
          const float cm = __shfl(cl, o);   // c for my o
          float4* sp = (float4*)&s_lds[b*(OC*OD) + sbase];
          float4 sv = *sp;
          sv.x += cm*usav[b][0]; sv.y += cm*usav[b][1];
          sv.z += cm*usav[b][2]; sv.w += cm*usav[b][3];
          *sp = sv;
        }
        __syncthreads();   // agr_s rows reused next ii: order reads vs writes
      }
    }
    __syncthreads();       // protect x_h restage (and s zero-init on g==0)
  }

  // flush per-wg partial s (coalesced float4, un-swizzled to logical d)
  const float scale = (ITER == 0) ? (1.0f/64.0f) : 1.0f;
  float* pp = part + (size_t)(ci*4 + bq) * PARTBLK;
#pragma unroll
  for (int b = 0; b < NBW; ++b) {
    float4 sv = *(float4*)&s_lds[b*(OC*OD) + sbase];
    float4 st;
    st.x = sv.x*scale; st.y = sv.y*scale; st.z = sv.z*scale; st.w = sv.w*scale;
    *(float4*)&pp[((size_t)b*OC + o)*OD + d0] = st;
  }
}

// Sum partials over i-chunks and apply squash. One 64-thr block per (b,o):
// lanes 0..31 = d; the two 32-lane halves split the chunk range.
__global__ __launch_bounds__(64)
void caps_reduce(const float* __restrict__ part, int nchunk, float* __restrict__ vout)
{
  const int r  = blockIdx.x;           // b*OC + o, 0..2047
  const int b  = r >> 6, o = r & 63;
  const int bq = b >> 3, bl = b & 7;   // b-quarter, local b
  const int d  = threadIdx.x & 31;
  const int h  = threadIdx.x >> 5;
  const size_t cellp = ((size_t)(bl*OC + o))*OD + d;
  const int half = nchunk >> 1;
  const float* p = part + ((size_t)(h*half)*4 + bq)*PARTBLK + cellp;
  float s = 0.f;
#pragma unroll 4
  for (int w = 0; w < half; ++w) s += p[(size_t)w*4*PARTBLK];
  s += __shfl_xor(s, 32);              // combine the two halves
  float n2 = s*s;
#pragma unroll
  for (int off = 1; off < 32; off <<= 1) n2 += __shfl_xor(n2, off);
  const float n = sqrtf(n2);
  const float f = n2 / ((1.f + n2)*(n + 1e-8f));   // squash, matches ref
  if (h == 0) vout[(size_t)r*OD + d] = s*f;
}

extern "C" void kernel_launch(void* const* d_in, const int* in_sizes, int n_in,
                              void* d_out, int out_size, void* d_ws, size_t ws_size,
                              hipStream_t stream)
{
  const float* xg = (const float*)d_in[0];
  const float* Wg = (const float*)d_in[1];
  float* out = (float*)d_out;

  const size_t bbuf_bytes = (size_t)NB*IC*OC*sizeof(float);   // 16 MB logits
  const size_t v_bytes    = (size_t)NB*OC*OD*sizeof(float);   // 256 KB
  int nchunk = NCHUNK;                                        // part = 32 MB
  while (nchunk > 16 &&
         ((size_t)nchunk*4*PARTBLK*sizeof(float) + bbuf_bytes + v_bytes) > ws_size)
    nchunk >>= 1;
  const int chunk = IC / nchunk;
  const int nwg = nchunk * 4;

  float* part = (float*)d_ws;
  float* bbuf = (float*)((char*)d_ws + (size_t)nwg*PARTBLK*sizeof(float));
  float* vbuf = (float*)((char*)bbuf + bbuf_bytes);

  // iter 1: c = 1/64 exactly -> plain sum of u_hat
  caps_pass<0><<<nwg, 512, 0, stream>>>(xg, Wg, nullptr, nullptr, nullptr, part, chunk, nchunk);
  caps_reduce<<<NB*OC, 64, 0, stream>>>(part, nchunk, vbuf);
  // iter 2: A1 = u.v1, c = softmax(A1); store A1
  caps_pass<1><<<nwg, 512, 0, stream>>>(xg, Wg, vbuf, nullptr, bbuf, part, chunk, nchunk);
  caps_reduce<<<NB*OC, 64, 0, stream>>>(part, nchunk, vbuf);
  // iter 3: c = softmax(A1 + u.v2)
  caps_pass<2><<<nwg, 512, 0, stream>>>(xg, Wg, vbuf, bbuf, nullptr, part, chunk, nchunk);
  caps_reduce<<<NB*OC, 64, 0, stream>>>(part, nchunk, out);
}